// Round 4
// baseline (140.375 us; speedup 1.0000x reference)
//
#include <hip/hip_runtime.h>
#include <cstddef>

#define EPS 1e-9f
#define REG_MAX 16
#define TOPK 13
#define MAXL 8400

__device__ __forceinline__ float sigmoidf(float x){ return 1.0f/(1.0f+expf(-x)); }
__device__ __forceinline__ float bcef(float l, float t){
    return fmaxf(l,0.0f) - l*t + log1pf(expf(-fabsf(l)));
}
__device__ __forceinline__ float pow6f(float x){ float x2=x*x; return x2*x2*x2; }

// K1: DFL softmax decode -> pred_bboxes in anchor_s units; sigmoid(pred_scores)
__global__ void k_decode(const float* __restrict__ pred_scores,
                         const float* __restrict__ pred_distri,
                         const float* __restrict__ anchor_points,
                         const float* __restrict__ stride_t,
                         float* __restrict__ pred_bboxes,
                         float* __restrict__ sig,
                         int B, int L)
{
    int idx = blockIdx.x*blockDim.x + threadIdx.x;
    if (idx >= B*L) return;
    int l = idx % L;
    float v[68];
    const float4* pd4 = (const float4*)(pred_distri + (size_t)idx*68);
    #pragma unroll
    for (int i=0;i<17;i++){ float4 q = pd4[i]; v[4*i]=q.x; v[4*i+1]=q.y; v[4*i+2]=q.z; v[4*i+3]=q.w; }
    float dist[4];
    #pragma unroll
    for (int s=0;s<4;s++){
        float m = -1e30f;
        #pragma unroll
        for (int i=0;i<=REG_MAX;i++) m = fmaxf(m, v[s*17+i]);
        float sum=0.f, ws=0.f;
        #pragma unroll
        for (int i=0;i<=REG_MAX;i++){ float e = expf(v[s*17+i]-m); sum+=e; ws += e*(float)i; }
        dist[s] = ws/sum;
    }
    float st = stride_t[l];
    float ax = anchor_points[2*l]/st, ay = anchor_points[2*l+1]/st;
    float4 box = make_float4(ax-dist[0], ay-dist[1], ax+dist[2], ay+dist[3]);
    ((float4*)pred_bboxes)[idx] = box;
    sig[idx] = sigmoidf(pred_scores[idx]);
}

// K2: one block per (b,n). Round 3 rewrite: register-resident per-thread
// sorted top-13 (static-unrolled bubble insert, exact jax.lax.top_k
// tie-break: higher val, then lower index), then 13 head-merge rounds over
// 256 thread heads (shfl butterfly + 4-entry LDS combine). No smet LDS,
// no per-round 8400 scans. in_gt flag packed into bit0 of index (order-
// preserving since (l<<1|ing) is monotone in l).
__global__ void k_assign_topk(const float* __restrict__ pred_bboxes,
                              const float* __restrict__ sig,
                              const float* __restrict__ anchor_points,
                              const float* __restrict__ stride_t,
                              const float* __restrict__ gt_bboxes,
                              const float* __restrict__ pad_mask,
                              float* __restrict__ ious,
                              unsigned char* __restrict__ maskA,
                              int B,int N,int L)
{
    __shared__ float wv[4];
    __shared__ int   wi[4];
    int bn = blockIdx.x; int b = bn / N; int n = bn % N;
    const float4 gb = ((const float4*)gt_bboxes)[bn];
    float gx1=gb.x, gy1=gb.y, gx2=gb.z, gy2=gb.w;
    float ag = (gx2-gx1)*(gy2-gy1);
    int tid = threadIdx.x;
    bool valid = pad_mask[bn] > 0.f;

    float lv[TOPK]; int li[TOPK];
    #pragma unroll
    for (int k=0;k<TOPK;k++){ lv[k]=-1.f; li[k]=0x7fffffff; }

    for (int l=tid; l<L; l+=256){
        float4 pb = ((const float4*)pred_bboxes)[b*L + l];
        float st = stride_t[l];
        float p0 = pb.x*st, p1 = pb.y*st, p2 = pb.z*st, p3 = pb.w*st;
        float iw = fmaxf(fminf(gx2,p2)-fmaxf(gx1,p0), 0.f);
        float ih = fmaxf(fminf(gy2,p3)-fmaxf(gy1,p1), 0.f);
        float inter = iw*ih;
        float ap = (p2-p0)*(p3-p1);
        float iou = inter/(ag+ap-inter+EPS);
        ious[(size_t)bn*L + l] = iou;
        if (valid){
            float apx = anchor_points[2*l], apy = anchor_points[2*l+1];
            bool ing = (apx-gx1>EPS)&&(apy-gy1>EPS)&&(gx2-apx>EPS)&&(gy2-apy>EPS);
            float v = ing ? sig[b*L+l]*pow6f(iou) : 0.0f;
            int   pi = (l<<1) | (ing?1:0);
            // beats current worst? (full comparator; list idx are all lower
            // scan-order except via displacement chains, handled below)
            if (v>lv[TOPK-1] || (v==lv[TOPK-1] && pi<li[TOPK-1])){
                float cv=v; int ci=pi;
                #pragma unroll
                for (int k=0;k<TOPK;k++){
                    bool better = (cv>lv[k]) || (cv==lv[k] && ci<li[k]);
                    if (better){
                        float tv=lv[k]; lv[k]=cv; cv=tv;
                        int   ti=li[k]; li[k]=ci; ci=ti;
                    }
                }
            }
        }
    }
    if (!valid) return;
    // 13 merge rounds over the 256 heads (each thread's head = lv[0]/li[0]).
    // Every thread has >=32 real candidates, so heads are never sentinels.
    for (int r=0;r<TOPK;r++){
        float bv=lv[0]; int bp=li[0];
        #pragma unroll
        for (int off=32; off>0; off>>=1){
            float ov = __shfl_xor(bv, off);
            int   op = __shfl_xor(bp, off);
            if (ov>bv || (ov==bv && op<bp)){ bv=ov; bp=op; }
        }
        if ((tid&63)==0){ wv[tid>>6]=bv; wi[tid>>6]=bp; }
        __syncthreads();
        float fv=wv[0]; int fp=wi[0];
        #pragma unroll
        for (int w2=1;w2<4;w2++){
            if (wv[w2]>fv || (wv[w2]==fv && wi[w2]<fp)){ fv=wv[w2]; fp=wi[w2]; }
        }
        if (li[0]==fp){ // unique owner (anchor indices unique across threads)
            if (fp&1){ int l = fp>>1; maskA[(size_t)(b*L+l)*N + n] = 1; }
            #pragma unroll
            for (int k=0;k<TOPK-1;k++){ lv[k]=lv[k+1]; li[k]=li[k+1]; }
            lv[TOPK-1]=-1.f; li[TOPK-1]=0x7fffffff;
        }
        __syncthreads();
    }
}

// K3: per anchor: count assigned GTs; if >1 replace column with onehot(argmax_n iou)
__global__ void k_resolve(const unsigned char* __restrict__ maskA,
                          const float* __restrict__ ious,
                          unsigned int* __restrict__ words,
                          int B,int N,int L)
{
    int idx = blockIdx.x*blockDim.x + threadIdx.x;
    if (idx >= B*L) return;
    int b = idx / L, l = idx % L;
    const unsigned char* row = maskA + (size_t)idx*N;
    unsigned int w=0; int cnt=0;
    for (int n=0;n<N;n++){ if (row[n]){ w |= 1u<<n; cnt++; } }
    if (cnt > 1){
        float bv=-1e30f; int bbest=0;
        for (int n=0;n<N;n++){
            float vv = ious[((size_t)(b*N+n))*L + l];
            if (vv > bv){ bv=vv; bbest=n; }
        }
        w = 1u<<bbest;
    }
    words[idx] = w;
}

// K4: per (b,n): rowmax of metric*mask and iou*mask over L
__global__ void k_rowmax(const unsigned int* __restrict__ words,
                         const float* __restrict__ ious,
                         const float* __restrict__ sig,
                         float* __restrict__ rowmax_m,
                         float* __restrict__ rowmax_iou,
                         int B,int N,int L)
{
    __shared__ float rm[256], rio[256];
    int bn = blockIdx.x; int b = bn/N; int n = bn%N;
    int tid=threadIdx.x;
    float mm=0.f, mi=0.f;
    for (int l=tid;l<L;l+=256){
        unsigned int w = words[b*L+l];
        if ((w>>n)&1u){
            float iou = ious[(size_t)bn*L+l];
            float met = sig[b*L+l]*pow6f(iou);
            mm = fmaxf(mm, met); mi = fmaxf(mi, iou);
        }
    }
    rm[tid]=mm; rio[tid]=mi; __syncthreads();
    for (int s=128;s>0;s>>=1){
        if (tid<s){ rm[tid]=fmaxf(rm[tid],rm[tid+s]); rio[tid]=fmaxf(rio[tid],rio[tid+s]); }
        __syncthreads();
    }
    if (tid==0){ rowmax_m[bn]=rm[0]; rowmax_iou[bn]=rio[0]; }
}

// K5: per-anchor loss terms, block-reduced into 8 partial sums per block
__global__ void k_loss(const float* __restrict__ pred_scores,
                       const float* __restrict__ pred_distri,
                       const float* __restrict__ pose_logits,
                       const float* __restrict__ anchor_points,
                       const float* __restrict__ stride_t,
                       const float* __restrict__ gt_bboxes,
                       const float* __restrict__ gt_poses,
                       const float* __restrict__ sigmas,
                       const int*   __restrict__ gt_class,
                       const float* __restrict__ pred_bboxes,
                       const float* __restrict__ sig,
                       const float* __restrict__ ious,
                       const unsigned int* __restrict__ words,
                       const float* __restrict__ rowmax_m,
                       const float* __restrict__ rowmax_iou,
                       float* __restrict__ partials,
                       int B,int N,int L,int J)
{
    int idx = blockIdx.x*blockDim.x + threadIdx.x;
    float a_score=0, a_cls=0, a_giou=0, a_dfl=0, a_pos=0, a_kmf=0, a_preg=0, a_pcls=0;
    if (idx < B*L){
        int b=idx/L, l=idx%L;
        unsigned int w = words[idx];
        bool pos = (w!=0u);
        int gi = pos ? (__ffs(w)-1) : 0;
        float score = 0.f;
        unsigned int ww=w;
        while (ww){
            int n = __ffs(ww)-1; ww &= ww-1u;
            float iou = ious[((size_t)(b*N+n))*L + l];
            float met = sig[idx]*pow6f(iou);
            float vv = met/(rowmax_m[b*N+n]+EPS)*rowmax_iou[b*N+n];
            score = fmaxf(score, vv);
        }
        int acls = pos ? gt_class[b*N+gi] : 1; // NUM_CLASSES=1 sentinel when neg
        float assigned = (pos && acls==0) ? score : 0.f;
        float logit = pred_scores[idx];
        float sg = sig[idx];
        float wg = sg - assigned; wg *= wg;
        a_cls = wg * bcef(logit, assigned);
        a_score = assigned;
        if (pos){
            a_pos = 1.f;
            float st = stride_t[l];
            const float4 gb4 = ((const float4*)gt_bboxes)[b*N+gi];
            float ab0=gb4.x/st, ab1=gb4.y/st, ab2=gb4.z/st, ab3=gb4.w/st;
            float area = (ab2-ab0)*(ab3-ab1);
            float apx = anchor_points[2*l]/st, apy = anchor_points[2*l+1]/st;
            float bw = assigned; // bbox_w = assigned_scores.sum(-1)*posf
            if (bw > 0.f){
                float4 pb = ((const float4*)pred_bboxes)[idx];
                float iw = fmaxf(fminf(pb.z,ab2)-fmaxf(pb.x,ab0),0.f);
                float ih = fmaxf(fminf(pb.w,ab3)-fmaxf(pb.y,ab1),0.f);
                float inter=iw*ih;
                float a1=(pb.z-pb.x)*(pb.w-pb.y);
                float a2=(ab2-ab0)*(ab3-ab1);
                float uni=a1+a2-inter+EPS;
                float iou=inter/uni;
                float cw=fmaxf(pb.z,ab2)-fminf(pb.x,ab0);
                float ch=fmaxf(pb.w,ab3)-fminf(pb.y,ab1);
                float ac=cw*ch+EPS;
                float g = 1.f-(iou-(ac-uni)/ac);
                a_giou = g*bw;
                // DFL
                float t4[4] = { apx-ab0, apy-ab1, ab2-apx, ab3-apy };
                const float* pdist = pred_distri + (size_t)idx*68;
                float dfl=0.f;
                #pragma unroll
                for (int s2=0;s2<4;s2++){
                    float tt = fminf(fmaxf(t4[s2],0.f),(float)REG_MAX-0.01f);
                    int tl = (int)floorf(tt);
                    float wl = (float)tl + 1.f - tt;
                    float m=-1e30f;
                    for (int i=0;i<=REG_MAX;i++) m=fmaxf(m,pdist[s2*17+i]);
                    float se=0.f;
                    for (int i=0;i<=REG_MAX;i++) se+=expf(pdist[s2*17+i]-m);
                    float lse = m + logf(se);
                    float ll = -(pdist[s2*17+tl]-lse);
                    float lr = -(pdist[s2*17+tl+1]-lse);
                    dfl += ll*wl + lr*(1.f-wl);
                }
                a_dfl = dfl*0.25f*bw;
            }
            // pose (only pos anchors contribute: every term gated by posf/kmf)
            const float* gp = gt_poses + ((size_t)(b*N+gi))*J*3;
            const float* pl = pose_logits + (size_t)idx*J*3;
            for (int j=0;j<J;j++){
                float gx=gp[3*j]/st, gy=gp[3*j+1]/st, vis=gp[3*j+2];
                float px=pl[3*j]+apx, py=pl[3*j+1]+apy, pz=pl[3*j+2];
                float kmf = (vis!=0.f)?1.f:0.f;
                float dx=px-gx, dy=py-gy;
                float d = dx*dx+dy*dy;
                float s2g = 2.f*sigmas[j]; s2g*=s2g;
                float e = d/s2g/(area+EPS)/2.f;
                a_preg += (1.f-expf(-e))*kmf;
                a_kmf  += kmf;
                a_pcls += bcef(pz, kmf);
            }
        }
    }
    __shared__ float red[256];
    float acc[8] = {a_score,a_cls,a_giou,a_dfl,a_pos,a_kmf,a_preg,a_pcls};
    #pragma unroll
    for (int k=0;k<8;k++){
        red[threadIdx.x]=acc[k]; __syncthreads();
        for (int s=128;s>0;s>>=1){
            if (threadIdx.x<s) red[threadIdx.x]+=red[threadIdx.x+s];
            __syncthreads();
        }
        if (threadIdx.x==0) partials[(size_t)blockIdx.x*8+k]=red[0];
        __syncthreads();
    }
}

// K6: deterministic parallel final reduction + loss assembly -> 7 floats
__global__ void k_final(const float* __restrict__ partials, int nblk, int J,
                        float* __restrict__ out)
{
    __shared__ float red[256][9]; // pad to 9 to avoid bank conflicts
    int tid = threadIdx.x;
    float acc[8] = {0,0,0,0,0,0,0,0};
    for (int i=tid; i<nblk; i+=256){
        const float4* p = (const float4*)(partials + (size_t)i*8);
        float4 a = p[0], b = p[1];
        acc[0]+=a.x; acc[1]+=a.y; acc[2]+=a.z; acc[3]+=a.w;
        acc[4]+=b.x; acc[5]+=b.y; acc[6]+=b.z; acc[7]+=b.w;
    }
    #pragma unroll
    for (int k=0;k<8;k++) red[tid][k]=acc[k];
    __syncthreads();
    for (int s=128;s>0;s>>=1){
        if (tid<s){
            #pragma unroll
            for (int k=0;k<8;k++) red[tid][k]+=red[tid+s][k];
        }
        __syncthreads();
    }
    if (tid==0){
        float ass  = fmaxf(red[0][0],1.f);
        float lcls = red[0][1]/ass;
        float liou = red[0][2]/ass;
        float ldfl = red[0][3]/ass;
        float npk  = fmaxf(red[0][4]*(float)J,1.f);
        float factor = npk/(red[0][5]+EPS);
        float preg = factor*red[0][6]/npk;
        float pcls = red[0][7]/npk;
        float loss = lcls + 2.5f*liou + 0.5f*ldfl + pcls + preg;
        out[0]=loss; out[1]=lcls; out[2]=liou; out[3]=ldfl;
        out[4]=pcls; out[5]=preg; out[6]=loss;
    }
}

extern "C" void kernel_launch(void* const* d_in, const int* in_sizes, int n_in,
                              void* d_out, int out_size, void* d_ws, size_t ws_size,
                              hipStream_t stream)
{
    const float* pred_scores   = (const float*)d_in[0];
    const float* pred_distri   = (const float*)d_in[1];
    const float* pose_logits   = (const float*)d_in[2];
    const float* anchor_points = (const float*)d_in[3];
    const float* stride_t      = (const float*)d_in[4];
    const float* gt_bboxes     = (const float*)d_in[5];
    const float* pad_mask      = (const float*)d_in[6];
    const float* gt_poses      = (const float*)d_in[7];
    const float* sigmas        = (const float*)d_in[8];
    const int*   gt_class      = (const int*)d_in[9];

    int L = in_sizes[3]/2;
    int B = in_sizes[0]/L;
    int N = in_sizes[5]/(B*4);
    int J = in_sizes[8];

    char* ws = (char*)d_ws;
    size_t off=0;
    auto alloc=[&](size_t bytes)->void*{
        size_t cur=off; off += (bytes+255)/256*256; return (void*)(ws+cur);
    };
    float* ious         = (float*)alloc((size_t)B*N*L*4);
    float* pred_bboxes  = (float*)alloc((size_t)B*L*4*4);
    float* sig          = (float*)alloc((size_t)B*L*4);
    unsigned char* maskA= (unsigned char*)alloc((size_t)B*L*N);
    unsigned int* words = (unsigned int*)alloc((size_t)B*L*4);
    float* rowmax_m     = (float*)alloc((size_t)B*N*4);
    float* rowmax_i     = (float*)alloc((size_t)B*N*4);
    int nblk = (B*L+255)/256;
    float* partials     = (float*)alloc((size_t)nblk*8*4);
    (void)ws_size; (void)n_in; (void)out_size;

    hipMemsetAsync(maskA, 0, (size_t)B*L*N, stream);
    k_decode<<<nblk,256,0,stream>>>(pred_scores,pred_distri,anchor_points,stride_t,
                                    pred_bboxes,sig,B,L);
    k_assign_topk<<<B*N,256,0,stream>>>(pred_bboxes,sig,anchor_points,stride_t,
                                        gt_bboxes,pad_mask,ious,maskA,B,N,L);
    k_resolve<<<nblk,256,0,stream>>>(maskA,ious,words,B,N,L);
    k_rowmax<<<B*N,256,0,stream>>>(words,ious,sig,rowmax_m,rowmax_i,B,N,L);
    k_loss<<<nblk,256,0,stream>>>(pred_scores,pred_distri,pose_logits,anchor_points,
                                  stride_t,gt_bboxes,gt_poses,sigmas,gt_class,
                                  pred_bboxes,sig,ious,words,rowmax_m,rowmax_i,
                                  partials,B,N,L,J);
    k_final<<<1,256,0,stream>>>(partials,nblk,J,(float*)d_out);
}

// Round 5
// 132.434 us; speedup vs baseline: 1.0600x; 1.0600x over previous
//
#include <hip/hip_runtime.h>
#include <cstddef>

#define EPS 1e-9f
#define REG_MAX 16
#define TOPK 13
#define MAXL 8400
#define TPB 1024
#define LLEN 9   // ceil(MAXL/TPB): max candidates per thread in K2

__device__ __forceinline__ float sigmoidf(float x){ return 1.0f/(1.0f+expf(-x)); }
__device__ __forceinline__ float bcef(float l, float t){
    return fmaxf(l,0.0f) - l*t + log1pf(expf(-fabsf(l)));
}
__device__ __forceinline__ float pow6f(float x){ float x2=x*x; return x2*x2*x2; }

// K1: DFL softmax decode -> pred_bboxes in anchor_s units; sigmoid(pred_scores)
__global__ void k_decode(const float* __restrict__ pred_scores,
                         const float* __restrict__ pred_distri,
                         const float* __restrict__ anchor_points,
                         const float* __restrict__ stride_t,
                         float* __restrict__ pred_bboxes,
                         float* __restrict__ sig,
                         int B, int L)
{
    int idx = blockIdx.x*blockDim.x + threadIdx.x;
    if (idx >= B*L) return;
    int l = idx % L;
    float v[68];
    const float4* pd4 = (const float4*)(pred_distri + (size_t)idx*68);
    #pragma unroll
    for (int i=0;i<17;i++){ float4 q = pd4[i]; v[4*i]=q.x; v[4*i+1]=q.y; v[4*i+2]=q.z; v[4*i+3]=q.w; }
    float dist[4];
    #pragma unroll
    for (int s=0;s<4;s++){
        float m = -1e30f;
        #pragma unroll
        for (int i=0;i<=REG_MAX;i++) m = fmaxf(m, v[s*17+i]);
        float sum=0.f, ws=0.f;
        #pragma unroll
        for (int i=0;i<=REG_MAX;i++){ float e = expf(v[s*17+i]-m); sum+=e; ws += e*(float)i; }
        dist[s] = ws/sum;
    }
    float st = stride_t[l];
    float ax = anchor_points[2*l]/st, ay = anchor_points[2*l+1]/st;
    float4 box = make_float4(ax-dist[0], ay-dist[1], ax+dist[2], ay+dist[3]);
    ((float4*)pred_bboxes)[idx] = box;
    sig[idx] = sigmoidf(pred_scores[idx]);
}

// K2: one block of 1024 threads per (b,n). Round 4: full occupancy
// (512 blocks x 16 waves = 32 waves/CU) + per-thread candidate count cut
// 33 -> 9 (sorted-9 register list; a thread owns <=9 candidates so 9 slots
// are provably sufficient for the global top-13). Merge: 13 rounds of
// 64-lane shfl butterfly + 16-wave LDS combine with the exact
// jax.lax.top_k comparator (higher val, then lower packed index).
// in_gt flag in bit0 of packed index ((l<<1|ing), monotone in l).
__global__ void k_assign_topk(const float* __restrict__ pred_bboxes,
                              const float* __restrict__ sig,
                              const float* __restrict__ anchor_points,
                              const float* __restrict__ stride_t,
                              const float* __restrict__ gt_bboxes,
                              const float* __restrict__ pad_mask,
                              float* __restrict__ ious,
                              unsigned char* __restrict__ maskA,
                              int B,int N,int L)
{
    __shared__ float wv[16];
    __shared__ int   wi[16];
    int bn = blockIdx.x; int b = bn / N; int n = bn % N;
    const float4 gb = ((const float4*)gt_bboxes)[bn];
    float gx1=gb.x, gy1=gb.y, gx2=gb.z, gy2=gb.w;
    float ag = (gx2-gx1)*(gy2-gy1);
    int tid = threadIdx.x;
    bool valid = pad_mask[bn] > 0.f;

    float lv[LLEN]; int li[LLEN];
    #pragma unroll
    for (int k=0;k<LLEN;k++){ lv[k]=-1.f; li[k]=0x7fffffff; }

    for (int l=tid; l<L; l+=TPB){
        float4 pb = ((const float4*)pred_bboxes)[b*L + l];
        float st = stride_t[l];
        float p0 = pb.x*st, p1 = pb.y*st, p2 = pb.z*st, p3 = pb.w*st;
        float iw = fmaxf(fminf(gx2,p2)-fmaxf(gx1,p0), 0.f);
        float ih = fmaxf(fminf(gy2,p3)-fmaxf(gy1,p1), 0.f);
        float inter = iw*ih;
        float ap = (p2-p0)*(p3-p1);
        float iou = inter/(ag+ap-inter+EPS);
        ious[(size_t)bn*L + l] = iou;
        if (valid){
            float apx = anchor_points[2*l], apy = anchor_points[2*l+1];
            bool ing = (apx-gx1>EPS)&&(apy-gy1>EPS)&&(gx2-apx>EPS)&&(gy2-apy>EPS);
            float v = ing ? sig[b*L+l]*pow6f(iou) : 0.0f;
            int   pi = (l<<1) | (ing?1:0);
            float cv=v; int ci=pi;
            #pragma unroll
            for (int k=0;k<LLEN;k++){
                bool better = (cv>lv[k]) || (cv==lv[k] && ci<li[k]);
                if (better){
                    float tv=lv[k]; lv[k]=cv; cv=tv;
                    int   ti=li[k]; li[k]=ci; ci=ti;
                }
            }
        }
    }
    if (!valid) return;
    // 13 merge rounds over the 1024 heads. Sentinel heads (-1) never win:
    // >0 real candidates always remain (8400 >> 13).
    for (int r=0;r<TOPK;r++){
        float bv=lv[0]; int bp=li[0];
        #pragma unroll
        for (int off=32; off>0; off>>=1){
            float ov = __shfl_xor(bv, off);
            int   op = __shfl_xor(bp, off);
            if (ov>bv || (ov==bv && op<bp)){ bv=ov; bp=op; }
        }
        if ((tid&63)==0){ wv[tid>>6]=bv; wi[tid>>6]=bp; }
        __syncthreads();
        float fv=wv[0]; int fp=wi[0];
        #pragma unroll
        for (int w2=1;w2<16;w2++){
            if (wv[w2]>fv || (wv[w2]==fv && wi[w2]<fp)){ fv=wv[w2]; fp=wi[w2]; }
        }
        if (li[0]==fp){ // unique owner (packed anchor indices unique)
            if (fp&1){ int l = fp>>1; maskA[(size_t)(b*L+l)*N + n] = 1; }
            #pragma unroll
            for (int k=0;k<LLEN-1;k++){ lv[k]=lv[k+1]; li[k]=li[k+1]; }
            lv[LLEN-1]=-1.f; li[LLEN-1]=0x7fffffff;
        }
        __syncthreads();
    }
}

// K3: per anchor: count assigned GTs; if >1 replace column with onehot(argmax_n iou)
__global__ void k_resolve(const unsigned char* __restrict__ maskA,
                          const float* __restrict__ ious,
                          unsigned int* __restrict__ words,
                          int B,int N,int L)
{
    int idx = blockIdx.x*blockDim.x + threadIdx.x;
    if (idx >= B*L) return;
    int b = idx / L, l = idx % L;
    // row is 32 bytes, 16B-aligned (ws alloc 256-aligned, idx*32 offset)
    const uint4* row4 = (const uint4*)(maskA + (size_t)idx*N);
    uint4 r0 = row4[0], r1 = row4[1];
    unsigned int wd[8] = {r0.x,r0.y,r0.z,r0.w,r1.x,r1.y,r1.z,r1.w};
    unsigned int w=0; int cnt=0;
    #pragma unroll
    for (int q=0;q<8;q++){
        unsigned int v = wd[q];
        #pragma unroll
        for (int c=0;c<4;c++){
            if ((v>>(8*c))&0xffu){ w |= 1u<<(q*4+c); cnt++; }
        }
    }
    if (cnt > 1){
        float bv=-1e30f; int bbest=0;
        for (int n=0;n<N;n++){
            float vv = ious[((size_t)(b*N+n))*L + l];
            if (vv > bv){ bv=vv; bbest=n; }
        }
        w = 1u<<bbest;
    }
    words[idx] = w;
}

// K4: per (b,n): rowmax of metric*mask and iou*mask over L.
// Round 4: 1024 threads + shfl butterfly max (was 256 + LDS tree).
__global__ void k_rowmax(const unsigned int* __restrict__ words,
                         const float* __restrict__ ious,
                         const float* __restrict__ sig,
                         float* __restrict__ rowmax_m,
                         float* __restrict__ rowmax_iou,
                         int B,int N,int L)
{
    __shared__ float srm[16], srio[16];
    int bn = blockIdx.x; int b = bn/N; int n = bn%N;
    int tid=threadIdx.x;
    float mm=0.f, mi=0.f;
    for (int l=tid;l<L;l+=TPB){
        unsigned int w = words[b*L+l];
        if ((w>>n)&1u){
            float iou = ious[(size_t)bn*L+l];
            float met = sig[b*L+l]*pow6f(iou);
            mm = fmaxf(mm, met); mi = fmaxf(mi, iou);
        }
    }
    #pragma unroll
    for (int off=32; off>0; off>>=1){
        mm = fmaxf(mm, __shfl_xor(mm, off));
        mi = fmaxf(mi, __shfl_xor(mi, off));
    }
    if ((tid&63)==0){ srm[tid>>6]=mm; srio[tid>>6]=mi; }
    __syncthreads();
    if (tid==0){
        float fm=srm[0], fi=srio[0];
        #pragma unroll
        for (int w2=1;w2<16;w2++){ fm=fmaxf(fm,srm[w2]); fi=fmaxf(fi,srio[w2]); }
        rowmax_m[bn]=fm; rowmax_iou[bn]=fi;
    }
}

// K5: per-anchor loss terms, block-reduced into 8 partial sums per block.
// Round 4: per-wave shfl butterfly sums + single barrier (was 8 LDS trees,
// 72 barriers).
__global__ void k_loss(const float* __restrict__ pred_scores,
                       const float* __restrict__ pred_distri,
                       const float* __restrict__ pose_logits,
                       const float* __restrict__ anchor_points,
                       const float* __restrict__ stride_t,
                       const float* __restrict__ gt_bboxes,
                       const float* __restrict__ gt_poses,
                       const float* __restrict__ sigmas,
                       const int*   __restrict__ gt_class,
                       const float* __restrict__ pred_bboxes,
                       const float* __restrict__ sig,
                       const float* __restrict__ ious,
                       const unsigned int* __restrict__ words,
                       const float* __restrict__ rowmax_m,
                       const float* __restrict__ rowmax_iou,
                       float* __restrict__ partials,
                       int B,int N,int L,int J)
{
    int idx = blockIdx.x*blockDim.x + threadIdx.x;
    float a_score=0, a_cls=0, a_giou=0, a_dfl=0, a_pos=0, a_kmf=0, a_preg=0, a_pcls=0;
    if (idx < B*L){
        int b=idx/L, l=idx%L;
        unsigned int w = words[idx];
        bool pos = (w!=0u);
        int gi = pos ? (__ffs(w)-1) : 0;
        float score = 0.f;
        unsigned int ww=w;
        while (ww){
            int n = __ffs(ww)-1; ww &= ww-1u;
            float iou = ious[((size_t)(b*N+n))*L + l];
            float met = sig[idx]*pow6f(iou);
            float vv = met/(rowmax_m[b*N+n]+EPS)*rowmax_iou[b*N+n];
            score = fmaxf(score, vv);
        }
        int acls = pos ? gt_class[b*N+gi] : 1; // NUM_CLASSES=1 sentinel when neg
        float assigned = (pos && acls==0) ? score : 0.f;
        float logit = pred_scores[idx];
        float sg = sig[idx];
        float wg = sg - assigned; wg *= wg;
        a_cls = wg * bcef(logit, assigned);
        a_score = assigned;
        if (pos){
            a_pos = 1.f;
            float st = stride_t[l];
            const float4 gb4 = ((const float4*)gt_bboxes)[b*N+gi];
            float ab0=gb4.x/st, ab1=gb4.y/st, ab2=gb4.z/st, ab3=gb4.w/st;
            float area = (ab2-ab0)*(ab3-ab1);
            float apx = anchor_points[2*l]/st, apy = anchor_points[2*l+1]/st;
            float bw = assigned; // bbox_w = assigned_scores.sum(-1)*posf
            if (bw > 0.f){
                float4 pb = ((const float4*)pred_bboxes)[idx];
                float iw = fmaxf(fminf(pb.z,ab2)-fmaxf(pb.x,ab0),0.f);
                float ih = fmaxf(fminf(pb.w,ab3)-fmaxf(pb.y,ab1),0.f);
                float inter=iw*ih;
                float a1=(pb.z-pb.x)*(pb.w-pb.y);
                float a2=(ab2-ab0)*(ab3-ab1);
                float uni=a1+a2-inter+EPS;
                float iou=inter/uni;
                float cw=fmaxf(pb.z,ab2)-fminf(pb.x,ab0);
                float ch=fmaxf(pb.w,ab3)-fminf(pb.y,ab1);
                float ac=cw*ch+EPS;
                float g = 1.f-(iou-(ac-uni)/ac);
                a_giou = g*bw;
                // DFL
                float t4[4] = { apx-ab0, apy-ab1, ab2-apx, ab3-apy };
                const float* pdist = pred_distri + (size_t)idx*68;
                float dfl=0.f;
                #pragma unroll
                for (int s2=0;s2<4;s2++){
                    float tt = fminf(fmaxf(t4[s2],0.f),(float)REG_MAX-0.01f);
                    int tl = (int)floorf(tt);
                    float wl = (float)tl + 1.f - tt;
                    float m=-1e30f;
                    for (int i=0;i<=REG_MAX;i++) m=fmaxf(m,pdist[s2*17+i]);
                    float se=0.f;
                    for (int i=0;i<=REG_MAX;i++) se+=expf(pdist[s2*17+i]-m);
                    float lse = m + logf(se);
                    float ll = -(pdist[s2*17+tl]-lse);
                    float lr = -(pdist[s2*17+tl+1]-lse);
                    dfl += ll*wl + lr*(1.f-wl);
                }
                a_dfl = dfl*0.25f*bw;
            }
            // pose (only pos anchors contribute: every term gated by posf/kmf)
            const float* gp = gt_poses + ((size_t)(b*N+gi))*J*3;
            const float* pl = pose_logits + (size_t)idx*J*3;
            for (int j=0;j<J;j++){
                float gx=gp[3*j]/st, gy=gp[3*j+1]/st, vis=gp[3*j+2];
                float px=pl[3*j]+apx, py=pl[3*j+1]+apy, pz=pl[3*j+2];
                float kmf = (vis!=0.f)?1.f:0.f;
                float dx=px-gx, dy=py-gy;
                float d = dx*dx+dy*dy;
                float s2g = 2.f*sigmas[j]; s2g*=s2g;
                float e = d/s2g/(area+EPS)/2.f;
                a_preg += (1.f-expf(-e))*kmf;
                a_kmf  += kmf;
                a_pcls += bcef(pz, kmf);
            }
        }
    }
    float acc[8] = {a_score,a_cls,a_giou,a_dfl,a_pos,a_kmf,a_preg,a_pcls};
    #pragma unroll
    for (int k=0;k<8;k++){
        #pragma unroll
        for (int off=32; off>0; off>>=1) acc[k] += __shfl_xor(acc[k], off);
    }
    __shared__ float wsum[4][8];
    int wid = threadIdx.x>>6;
    if ((threadIdx.x&63)==0){
        #pragma unroll
        for (int k=0;k<8;k++) wsum[wid][k]=acc[k];
    }
    __syncthreads();
    if (threadIdx.x<8){
        float s = wsum[0][threadIdx.x]+wsum[1][threadIdx.x]
                + wsum[2][threadIdx.x]+wsum[3][threadIdx.x];
        partials[(size_t)blockIdx.x*8+threadIdx.x]=s;
    }
}

// K6: deterministic parallel final reduction + loss assembly -> 7 floats
__global__ void k_final(const float* __restrict__ partials, int nblk, int J,
                        float* __restrict__ out)
{
    __shared__ float red[256][9]; // pad to 9 to avoid bank conflicts
    int tid = threadIdx.x;
    float acc[8] = {0,0,0,0,0,0,0,0};
    for (int i=tid; i<nblk; i+=256){
        const float4* p = (const float4*)(partials + (size_t)i*8);
        float4 a = p[0], b = p[1];
        acc[0]+=a.x; acc[1]+=a.y; acc[2]+=a.z; acc[3]+=a.w;
        acc[4]+=b.x; acc[5]+=b.y; acc[6]+=b.z; acc[7]+=b.w;
    }
    #pragma unroll
    for (int k=0;k<8;k++) red[tid][k]=acc[k];
    __syncthreads();
    for (int s=128;s>0;s>>=1){
        if (tid<s){
            #pragma unroll
            for (int k=0;k<8;k++) red[tid][k]+=red[tid+s][k];
        }
        __syncthreads();
    }
    if (tid==0){
        float ass  = fmaxf(red[0][0],1.f);
        float lcls = red[0][1]/ass;
        float liou = red[0][2]/ass;
        float ldfl = red[0][3]/ass;
        float npk  = fmaxf(red[0][4]*(float)J,1.f);
        float factor = npk/(red[0][5]+EPS);
        float preg = factor*red[0][6]/npk;
        float pcls = red[0][7]/npk;
        float loss = lcls + 2.5f*liou + 0.5f*ldfl + pcls + preg;
        out[0]=loss; out[1]=lcls; out[2]=liou; out[3]=ldfl;
        out[4]=pcls; out[5]=preg; out[6]=loss;
    }
}

extern "C" void kernel_launch(void* const* d_in, const int* in_sizes, int n_in,
                              void* d_out, int out_size, void* d_ws, size_t ws_size,
                              hipStream_t stream)
{
    const float* pred_scores   = (const float*)d_in[0];
    const float* pred_distri   = (const float*)d_in[1];
    const float* pose_logits   = (const float*)d_in[2];
    const float* anchor_points = (const float*)d_in[3];
    const float* stride_t      = (const float*)d_in[4];
    const float* gt_bboxes     = (const float*)d_in[5];
    const float* pad_mask      = (const float*)d_in[6];
    const float* gt_poses      = (const float*)d_in[7];
    const float* sigmas        = (const float*)d_in[8];
    const int*   gt_class      = (const int*)d_in[9];

    int L = in_sizes[3]/2;
    int B = in_sizes[0]/L;
    int N = in_sizes[5]/(B*4);
    int J = in_sizes[8];

    char* ws = (char*)d_ws;
    size_t off=0;
    auto alloc=[&](size_t bytes)->void*{
        size_t cur=off; off += (bytes+255)/256*256; return (void*)(ws+cur);
    };
    float* ious         = (float*)alloc((size_t)B*N*L*4);
    float* pred_bboxes  = (float*)alloc((size_t)B*L*4*4);
    float* sig          = (float*)alloc((size_t)B*L*4);
    unsigned char* maskA= (unsigned char*)alloc((size_t)B*L*N);
    unsigned int* words = (unsigned int*)alloc((size_t)B*L*4);
    float* rowmax_m     = (float*)alloc((size_t)B*N*4);
    float* rowmax_i     = (float*)alloc((size_t)B*N*4);
    int nblk = (B*L+255)/256;
    float* partials     = (float*)alloc((size_t)nblk*8*4);
    (void)ws_size; (void)n_in; (void)out_size;

    hipMemsetAsync(maskA, 0, (size_t)B*L*N, stream);
    k_decode<<<nblk,256,0,stream>>>(pred_scores,pred_distri,anchor_points,stride_t,
                                    pred_bboxes,sig,B,L);
    k_assign_topk<<<B*N,TPB,0,stream>>>(pred_bboxes,sig,anchor_points,stride_t,
                                        gt_bboxes,pad_mask,ious,maskA,B,N,L);
    k_resolve<<<nblk,256,0,stream>>>(maskA,ious,words,B,N,L);
    k_rowmax<<<B*N,TPB,0,stream>>>(words,ious,sig,rowmax_m,rowmax_i,B,N,L);
    k_loss<<<nblk,256,0,stream>>>(pred_scores,pred_distri,pose_logits,anchor_points,
                                  stride_t,gt_bboxes,gt_poses,sigmas,gt_class,
                                  pred_bboxes,sig,ious,words,rowmax_m,rowmax_i,
                                  partials,B,N,L,J);
    k_final<<<1,256,0,stream>>>(partials,nblk,J,(float*)d_out);
}

// Round 6
// 107.266 us; speedup vs baseline: 1.3087x; 1.2346x over previous
//
#include <hip/hip_runtime.h>
#include <cstddef>

#define EPS 1e-9f
#define REG_MAX 16
#define TOPK 13
#define MAXL 8400
#define TPB 1024
#define CAP 1024   // max in-gt anchors per (b,n): 160px box covers <=598
#define LSLOT 16   // per-lane sorted slots in selection wave: ceil(CAP/64)

__device__ __forceinline__ float sigmoidf(float x){ return 1.0f/(1.0f+expf(-x)); }
__device__ __forceinline__ float bcef(float l, float t){
    return fmaxf(l,0.0f) - l*t + log1pf(expf(-fabsf(l)));
}
__device__ __forceinline__ float pow6f(float x){ float x2=x*x; return x2*x2*x2; }

// K1: DFL softmax decode -> pred_bboxes in anchor_s units; sigmoid(pred_scores)
__global__ void k_decode(const float* __restrict__ pred_scores,
                         const float* __restrict__ pred_distri,
                         const float* __restrict__ anchor_points,
                         const float* __restrict__ stride_t,
                         float* __restrict__ pred_bboxes,
                         float* __restrict__ sig,
                         int B, int L)
{
    int idx = blockIdx.x*blockDim.x + threadIdx.x;
    if (idx >= B*L) return;
    int l = idx % L;
    float v[68];
    const float4* pd4 = (const float4*)(pred_distri + (size_t)idx*68);
    #pragma unroll
    for (int i=0;i<17;i++){ float4 q = pd4[i]; v[4*i]=q.x; v[4*i+1]=q.y; v[4*i+2]=q.z; v[4*i+3]=q.w; }
    float dist[4];
    #pragma unroll
    for (int s=0;s<4;s++){
        float m = -1e30f;
        #pragma unroll
        for (int i=0;i<=REG_MAX;i++) m = fmaxf(m, v[s*17+i]);
        float sum=0.f, ws=0.f;
        #pragma unroll
        for (int i=0;i<=REG_MAX;i++){ float e = expf(v[s*17+i]-m); sum+=e; ws += e*(float)i; }
        dist[s] = ws/sum;
    }
    float st = stride_t[l];
    float ax = anchor_points[2*l]/st, ay = anchor_points[2*l+1]/st;
    float4 box = make_float4(ax-dist[0], ay-dist[1], ax+dist[2], ay+dist[3]);
    ((float4*)pred_bboxes)[idx] = box;
    sig[idx] = sigmoidf(pred_scores[idx]);
}

// K2, round 5 rewrite. Key fact: metric>0 <=> in_gt (center strictly inside),
// and mask_pos multiplies by in_gt — so zero-metric topk fills never set mask.
// Hence mask = top-min(13,cnt) of IN-GT candidates by (metric desc, l asc).
// Scan: compute IoU for all l (ious written for ALL n, padded too — needed by
// the is_max_iou fallback), compact in-gt candidates to LDS (atomic slot;
// order nondeterministic, but the comparator is an order-independent
// semilattice over unique indices => deterministic result).
// cnt<=13: all in-gt anchors masked, no selection. Else: ONE wave runs 13
// butterfly-argmax rounds (no __syncthreads) over per-lane sorted lists.
__global__ void k_assign_topk(const float* __restrict__ pred_bboxes,
                              const float* __restrict__ sig,
                              const float* __restrict__ anchor_points,
                              const float* __restrict__ stride_t,
                              const float* __restrict__ gt_bboxes,
                              const float* __restrict__ pad_mask,
                              float* __restrict__ ious,
                              unsigned char* __restrict__ maskA,
                              int B,int N,int L)
{
    __shared__ int   scnt;
    __shared__ float sval[CAP];
    __shared__ int   sidx[CAP];
    int bn = blockIdx.x; int b = bn / N; int n = bn % N;
    const float4 gb = ((const float4*)gt_bboxes)[bn];
    float gx1=gb.x, gy1=gb.y, gx2=gb.z, gy2=gb.w;
    float ag = (gx2-gx1)*(gy2-gy1);
    int tid = threadIdx.x;
    bool valid = pad_mask[bn] > 0.f;
    if (tid==0) scnt=0;
    __syncthreads();

    for (int l=tid; l<L; l+=TPB){
        float4 pb = ((const float4*)pred_bboxes)[b*L + l];
        float st = stride_t[l];
        float p0 = pb.x*st, p1 = pb.y*st, p2 = pb.z*st, p3 = pb.w*st;
        float iw = fmaxf(fminf(gx2,p2)-fmaxf(gx1,p0), 0.f);
        float ih = fmaxf(fminf(gy2,p3)-fmaxf(gy1,p1), 0.f);
        float inter = iw*ih;
        float ap = (p2-p0)*(p3-p1);
        float iou = inter/(ag+ap-inter+EPS);
        ious[(size_t)bn*L + l] = iou;
        if (valid){
            float apx = anchor_points[2*l], apy = anchor_points[2*l+1];
            bool ing = (apx-gx1>EPS)&&(apy-gy1>EPS)&&(gx2-apx>EPS)&&(gy2-apy>EPS);
            if (ing){
                float v = sig[b*L+l]*pow6f(iou);
                int slot = atomicAdd(&scnt, 1);
                if (slot < CAP){ sval[slot]=v; sidx[slot]=l; }
            }
        }
    }
    __syncthreads();
    if (!valid) return;
    int cnt = scnt < CAP ? scnt : CAP;

    if (cnt <= TOPK){
        // every in-gt candidate is in the top-13 (positives outrank all zeros)
        for (int i=tid; i<cnt; i+=TPB)
            maskA[(size_t)(b*L + sidx[i])*N + n] = 1;
        return;
    }
    if (tid >= 64) return;
    // per-lane sorted list over owned compacted entries (lane, lane+64, ...)
    float lv[LSLOT]; int li[LSLOT];
    #pragma unroll
    for (int k=0;k<LSLOT;k++){ lv[k]=-1.f; li[k]=0x7fffffff; }
    for (int i=tid; i<cnt; i+=64){
        float cv = sval[i]; int ci = sidx[i];
        #pragma unroll
        for (int k=0;k<LSLOT;k++){
            bool better = (cv>lv[k]) || (cv==lv[k] && ci<li[k]);
            if (better){
                float tv=lv[k]; lv[k]=cv; cv=tv;
                int   ti=li[k]; li[k]=ci; ci=ti;
            }
        }
    }
    // 13 iterative butterfly-argmax rounds, intra-wave only (no barriers)
    for (int r=0;r<TOPK;r++){
        float bv=lv[0]; int bl=li[0];
        #pragma unroll
        for (int off=32; off>0; off>>=1){
            float ov = __shfl_xor(bv, off);
            int   oi = __shfl_xor(bl, off);
            if (ov>bv || (ov==bv && oi<bl)){ bv=ov; bl=oi; }
        }
        if (li[0]==bl){ // unique owner (anchor indices unique)
            maskA[(size_t)(b*L + bl)*N + n] = 1;
            #pragma unroll
            for (int k=0;k<LSLOT-1;k++){ lv[k]=lv[k+1]; li[k]=li[k+1]; }
            lv[LSLOT-1]=-1.f; li[LSLOT-1]=0x7fffffff;
        }
    }
}

// K3: per anchor: count assigned GTs; if >1 replace column with onehot(argmax_n iou)
__global__ void k_resolve(const unsigned char* __restrict__ maskA,
                          const float* __restrict__ ious,
                          unsigned int* __restrict__ words,
                          int B,int N,int L)
{
    int idx = blockIdx.x*blockDim.x + threadIdx.x;
    if (idx >= B*L) return;
    int b = idx / L, l = idx % L;
    // row is 32 bytes, 16B-aligned (ws alloc 256-aligned, idx*32 offset)
    const uint4* row4 = (const uint4*)(maskA + (size_t)idx*N);
    uint4 r0 = row4[0], r1 = row4[1];
    unsigned int wd[8] = {r0.x,r0.y,r0.z,r0.w,r1.x,r1.y,r1.z,r1.w};
    unsigned int w=0; int cnt=0;
    #pragma unroll
    for (int q=0;q<8;q++){
        unsigned int v = wd[q];
        #pragma unroll
        for (int c=0;c<4;c++){
            if ((v>>(8*c))&0xffu){ w |= 1u<<(q*4+c); cnt++; }
        }
    }
    if (cnt > 1){
        float bv=-1e30f; int bbest=0;
        for (int n=0;n<N;n++){
            float vv = ious[((size_t)(b*N+n))*L + l];
            if (vv > bv){ bv=vv; bbest=n; }
        }
        w = 1u<<bbest;
    }
    words[idx] = w;
}

// K4: per (b,n): rowmax of metric*mask and iou*mask over L.
__global__ void k_rowmax(const unsigned int* __restrict__ words,
                         const float* __restrict__ ious,
                         const float* __restrict__ sig,
                         float* __restrict__ rowmax_m,
                         float* __restrict__ rowmax_iou,
                         int B,int N,int L)
{
    __shared__ float srm[16], srio[16];
    int bn = blockIdx.x; int b = bn/N; int n = bn%N;
    int tid=threadIdx.x;
    float mm=0.f, mi=0.f;
    for (int l=tid;l<L;l+=TPB){
        unsigned int w = words[b*L+l];
        if ((w>>n)&1u){
            float iou = ious[(size_t)bn*L+l];
            float met = sig[b*L+l]*pow6f(iou);
            mm = fmaxf(mm, met); mi = fmaxf(mi, iou);
        }
    }
    #pragma unroll
    for (int off=32; off>0; off>>=1){
        mm = fmaxf(mm, __shfl_xor(mm, off));
        mi = fmaxf(mi, __shfl_xor(mi, off));
    }
    if ((tid&63)==0){ srm[tid>>6]=mm; srio[tid>>6]=mi; }
    __syncthreads();
    if (tid==0){
        float fm=srm[0], fi=srio[0];
        #pragma unroll
        for (int w2=1;w2<16;w2++){ fm=fmaxf(fm,srm[w2]); fi=fmaxf(fi,srio[w2]); }
        rowmax_m[bn]=fm; rowmax_iou[bn]=fi;
    }
}

// K5: per-anchor loss terms, block-reduced into 8 partial sums per block.
__global__ void k_loss(const float* __restrict__ pred_scores,
                       const float* __restrict__ pred_distri,
                       const float* __restrict__ pose_logits,
                       const float* __restrict__ anchor_points,
                       const float* __restrict__ stride_t,
                       const float* __restrict__ gt_bboxes,
                       const float* __restrict__ gt_poses,
                       const float* __restrict__ sigmas,
                       const int*   __restrict__ gt_class,
                       const float* __restrict__ pred_bboxes,
                       const float* __restrict__ sig,
                       const float* __restrict__ ious,
                       const unsigned int* __restrict__ words,
                       const float* __restrict__ rowmax_m,
                       const float* __restrict__ rowmax_iou,
                       float* __restrict__ partials,
                       int B,int N,int L,int J)
{
    int idx = blockIdx.x*blockDim.x + threadIdx.x;
    float a_score=0, a_cls=0, a_giou=0, a_dfl=0, a_pos=0, a_kmf=0, a_preg=0, a_pcls=0;
    if (idx < B*L){
        int b=idx/L, l=idx%L;
        unsigned int w = words[idx];
        bool pos = (w!=0u);
        int gi = pos ? (__ffs(w)-1) : 0;
        float score = 0.f;
        unsigned int ww=w;
        while (ww){
            int n = __ffs(ww)-1; ww &= ww-1u;
            float iou = ious[((size_t)(b*N+n))*L + l];
            float met = sig[idx]*pow6f(iou);
            float vv = met/(rowmax_m[b*N+n]+EPS)*rowmax_iou[b*N+n];
            score = fmaxf(score, vv);
        }
        int acls = pos ? gt_class[b*N+gi] : 1; // NUM_CLASSES=1 sentinel when neg
        float assigned = (pos && acls==0) ? score : 0.f;
        float logit = pred_scores[idx];
        float sg = sig[idx];
        float wg = sg - assigned; wg *= wg;
        a_cls = wg * bcef(logit, assigned);
        a_score = assigned;
        if (pos){
            a_pos = 1.f;
            float st = stride_t[l];
            const float4 gb4 = ((const float4*)gt_bboxes)[b*N+gi];
            float ab0=gb4.x/st, ab1=gb4.y/st, ab2=gb4.z/st, ab3=gb4.w/st;
            float area = (ab2-ab0)*(ab3-ab1);
            float apx = anchor_points[2*l]/st, apy = anchor_points[2*l+1]/st;
            float bw = assigned; // bbox_w = assigned_scores.sum(-1)*posf
            if (bw > 0.f){
                float4 pb = ((const float4*)pred_bboxes)[idx];
                float iw = fmaxf(fminf(pb.z,ab2)-fmaxf(pb.x,ab0),0.f);
                float ih = fmaxf(fminf(pb.w,ab3)-fmaxf(pb.y,ab1),0.f);
                float inter=iw*ih;
                float a1=(pb.z-pb.x)*(pb.w-pb.y);
                float a2=(ab2-ab0)*(ab3-ab1);
                float uni=a1+a2-inter+EPS;
                float iou=inter/uni;
                float cw=fmaxf(pb.z,ab2)-fminf(pb.x,ab0);
                float ch=fmaxf(pb.w,ab3)-fminf(pb.y,ab1);
                float ac=cw*ch+EPS;
                float g = 1.f-(iou-(ac-uni)/ac);
                a_giou = g*bw;
                // DFL
                float t4[4] = { apx-ab0, apy-ab1, ab2-apx, ab3-apy };
                const float* pdist = pred_distri + (size_t)idx*68;
                float dfl=0.f;
                #pragma unroll
                for (int s2=0;s2<4;s2++){
                    float tt = fminf(fmaxf(t4[s2],0.f),(float)REG_MAX-0.01f);
                    int tl = (int)floorf(tt);
                    float wl = (float)tl + 1.f - tt;
                    float m=-1e30f;
                    for (int i=0;i<=REG_MAX;i++) m=fmaxf(m,pdist[s2*17+i]);
                    float se=0.f;
                    for (int i=0;i<=REG_MAX;i++) se+=expf(pdist[s2*17+i]-m);
                    float lse = m + logf(se);
                    float ll = -(pdist[s2*17+tl]-lse);
                    float lr = -(pdist[s2*17+tl+1]-lse);
                    dfl += ll*wl + lr*(1.f-wl);
                }
                a_dfl = dfl*0.25f*bw;
            }
            // pose (only pos anchors contribute: every term gated by posf/kmf)
            const float* gp = gt_poses + ((size_t)(b*N+gi))*J*3;
            const float* pl = pose_logits + (size_t)idx*J*3;
            for (int j=0;j<J;j++){
                float gx=gp[3*j]/st, gy=gp[3*j+1]/st, vis=gp[3*j+2];
                float px=pl[3*j]+apx, py=pl[3*j+1]+apy, pz=pl[3*j+2];
                float kmf = (vis!=0.f)?1.f:0.f;
                float dx=px-gx, dy=py-gy;
                float d = dx*dx+dy*dy;
                float s2g = 2.f*sigmas[j]; s2g*=s2g;
                float e = d/s2g/(area+EPS)/2.f;
                a_preg += (1.f-expf(-e))*kmf;
                a_kmf  += kmf;
                a_pcls += bcef(pz, kmf);
            }
        }
    }
    float acc[8] = {a_score,a_cls,a_giou,a_dfl,a_pos,a_kmf,a_preg,a_pcls};
    #pragma unroll
    for (int k=0;k<8;k++){
        #pragma unroll
        for (int off=32; off>0; off>>=1) acc[k] += __shfl_xor(acc[k], off);
    }
    __shared__ float wsum[4][8];
    int wid = threadIdx.x>>6;
    if ((threadIdx.x&63)==0){
        #pragma unroll
        for (int k=0;k<8;k++) wsum[wid][k]=acc[k];
    }
    __syncthreads();
    if (threadIdx.x<8){
        float s = wsum[0][threadIdx.x]+wsum[1][threadIdx.x]
                + wsum[2][threadIdx.x]+wsum[3][threadIdx.x];
        partials[(size_t)blockIdx.x*8+threadIdx.x]=s;
    }
}

// K6: deterministic parallel final reduction + loss assembly -> 7 floats
__global__ void k_final(const float* __restrict__ partials, int nblk, int J,
                        float* __restrict__ out)
{
    __shared__ float red[256][9]; // pad to 9 to avoid bank conflicts
    int tid = threadIdx.x;
    float acc[8] = {0,0,0,0,0,0,0,0};
    for (int i=tid; i<nblk; i+=256){
        const float4* p = (const float4*)(partials + (size_t)i*8);
        float4 a = p[0], b = p[1];
        acc[0]+=a.x; acc[1]+=a.y; acc[2]+=a.z; acc[3]+=a.w;
        acc[4]+=b.x; acc[5]+=b.y; acc[6]+=b.z; acc[7]+=b.w;
    }
    #pragma unroll
    for (int k=0;k<8;k++) red[tid][k]=acc[k];
    __syncthreads();
    for (int s=128;s>0;s>>=1){
        if (tid<s){
            #pragma unroll
            for (int k=0;k<8;k++) red[tid][k]+=red[tid+s][k];
        }
        __syncthreads();
    }
    if (tid==0){
        float ass  = fmaxf(red[0][0],1.f);
        float lcls = red[0][1]/ass;
        float liou = red[0][2]/ass;
        float ldfl = red[0][3]/ass;
        float npk  = fmaxf(red[0][4]*(float)J,1.f);
        float factor = npk/(red[0][5]+EPS);
        float preg = factor*red[0][6]/npk;
        float pcls = red[0][7]/npk;
        float loss = lcls + 2.5f*liou + 0.5f*ldfl + pcls + preg;
        out[0]=loss; out[1]=lcls; out[2]=liou; out[3]=ldfl;
        out[4]=pcls; out[5]=preg; out[6]=loss;
    }
}

extern "C" void kernel_launch(void* const* d_in, const int* in_sizes, int n_in,
                              void* d_out, int out_size, void* d_ws, size_t ws_size,
                              hipStream_t stream)
{
    const float* pred_scores   = (const float*)d_in[0];
    const float* pred_distri   = (const float*)d_in[1];
    const float* pose_logits   = (const float*)d_in[2];
    const float* anchor_points = (const float*)d_in[3];
    const float* stride_t      = (const float*)d_in[4];
    const float* gt_bboxes     = (const float*)d_in[5];
    const float* pad_mask      = (const float*)d_in[6];
    const float* gt_poses      = (const float*)d_in[7];
    const float* sigmas        = (const float*)d_in[8];
    const int*   gt_class      = (const int*)d_in[9];

    int L = in_sizes[3]/2;
    int B = in_sizes[0]/L;
    int N = in_sizes[5]/(B*4);
    int J = in_sizes[8];

    char* ws = (char*)d_ws;
    size_t off=0;
    auto alloc=[&](size_t bytes)->void*{
        size_t cur=off; off += (bytes+255)/256*256; return (void*)(ws+cur);
    };
    float* ious         = (float*)alloc((size_t)B*N*L*4);
    float* pred_bboxes  = (float*)alloc((size_t)B*L*4*4);
    float* sig          = (float*)alloc((size_t)B*L*4);
    unsigned char* maskA= (unsigned char*)alloc((size_t)B*L*N);
    unsigned int* words = (unsigned int*)alloc((size_t)B*L*4);
    float* rowmax_m     = (float*)alloc((size_t)B*N*4);
    float* rowmax_i     = (float*)alloc((size_t)B*N*4);
    int nblk = (B*L+255)/256;
    float* partials     = (float*)alloc((size_t)nblk*8*4);
    (void)ws_size; (void)n_in; (void)out_size;

    hipMemsetAsync(maskA, 0, (size_t)B*L*N, stream);
    k_decode<<<nblk,256,0,stream>>>(pred_scores,pred_distri,anchor_points,stride_t,
                                    pred_bboxes,sig,B,L);
    k_assign_topk<<<B*N,TPB,0,stream>>>(pred_bboxes,sig,anchor_points,stride_t,
                                        gt_bboxes,pad_mask,ious,maskA,B,N,L);
    k_resolve<<<nblk,256,0,stream>>>(maskA,ious,words,B,N,L);
    k_rowmax<<<B*N,TPB,0,stream>>>(words,ious,sig,rowmax_m,rowmax_i,B,N,L);
    k_loss<<<nblk,256,0,stream>>>(pred_scores,pred_distri,pose_logits,anchor_points,
                                  stride_t,gt_bboxes,gt_poses,sigmas,gt_class,
                                  pred_bboxes,sig,ious,words,rowmax_m,rowmax_i,
                                  partials,B,N,L,J);
    k_final<<<1,256,0,stream>>>(partials,nblk,J,(float*)d_out);
}

// Round 7
// 96.589 us; speedup vs baseline: 1.4533x; 1.1105x over previous
//
#include <hip/hip_runtime.h>
#include <cstddef>

#define EPS 1e-9f
#define REG_MAX 16
#define TOPK 13
#define MAXL 8400
#define TPB 1024
#define CAP 1024   // max in-gt anchors per (b,n): 160px box covers <=598
#define LSLOT 16   // per-lane sorted slots in selection wave: ceil(CAP/64)

__device__ __forceinline__ float sigmoidf(float x){ return 1.0f/(1.0f+expf(-x)); }
__device__ __forceinline__ float bcef(float l, float t){
    return fmaxf(l,0.0f) - l*t + log1pf(expf(-fabsf(l)));
}
__device__ __forceinline__ float pow6f(float x){ float x2=x*x; return x2*x2*x2; }

// K1: DFL softmax decode + sigmoid; also zeroes words / rowmax / pcnt
// (replaces the 40us runtime fillBuffer dispatch).
__global__ void k_decode(const float* __restrict__ pred_scores,
                         const float* __restrict__ pred_distri,
                         const float* __restrict__ anchor_points,
                         const float* __restrict__ stride_t,
                         float* __restrict__ pred_bboxes,
                         float* __restrict__ sig,
                         unsigned int* __restrict__ words,
                         unsigned int* __restrict__ rowmax_m,
                         unsigned int* __restrict__ rowmax_i,
                         int* __restrict__ pcnt,
                         int B, int N, int L)
{
    int idx = blockIdx.x*blockDim.x + threadIdx.x;
    if (idx >= B*L) return;
    if (idx < B*N){ rowmax_m[idx]=0u; rowmax_i[idx]=0u; }
    if (idx == 0) *pcnt = 0;
    words[idx] = 0u;
    int l = idx % L;
    float v[68];
    const float4* pd4 = (const float4*)(pred_distri + (size_t)idx*68);
    #pragma unroll
    for (int i=0;i<17;i++){ float4 q = pd4[i]; v[4*i]=q.x; v[4*i+1]=q.y; v[4*i+2]=q.z; v[4*i+3]=q.w; }
    float dist[4];
    #pragma unroll
    for (int s=0;s<4;s++){
        float m = -1e30f;
        #pragma unroll
        for (int i=0;i<=REG_MAX;i++) m = fmaxf(m, v[s*17+i]);
        float sum=0.f, ws=0.f;
        #pragma unroll
        for (int i=0;i<=REG_MAX;i++){ float e = expf(v[s*17+i]-m); sum+=e; ws += e*(float)i; }
        dist[s] = ws/sum;
    }
    float st = stride_t[l];
    float ax = anchor_points[2*l]/st, ay = anchor_points[2*l+1]/st;
    float4 box = make_float4(ax-dist[0], ay-dist[1], ax+dist[2], ay+dist[3]);
    ((float4*)pred_bboxes)[idx] = box;
    sig[idx] = sigmoidf(pred_scores[idx]);
}

// K2: mask = top-min(13,cnt) of IN-GT candidates (metric>0 <=> in_gt; zero-
// metric topk fills never set mask since mask_pos *= in_gt). Compact in-gt
// candidates to LDS, then one wave does 13 butterfly-argmax rounds.
// Round 6: writes bits straight into words via atomicOr (no maskA buffer).
__global__ void k_assign_topk(const float* __restrict__ pred_bboxes,
                              const float* __restrict__ sig,
                              const float* __restrict__ anchor_points,
                              const float* __restrict__ stride_t,
                              const float* __restrict__ gt_bboxes,
                              const float* __restrict__ pad_mask,
                              float* __restrict__ ious,
                              unsigned int* __restrict__ words,
                              int B,int N,int L)
{
    __shared__ int   scnt;
    __shared__ float sval[CAP];
    __shared__ int   sidx[CAP];
    int bn = blockIdx.x; int b = bn / N; int n = bn % N;
    const float4 gb = ((const float4*)gt_bboxes)[bn];
    float gx1=gb.x, gy1=gb.y, gx2=gb.z, gy2=gb.w;
    float ag = (gx2-gx1)*(gy2-gy1);
    int tid = threadIdx.x;
    bool valid = pad_mask[bn] > 0.f;
    if (tid==0) scnt=0;
    __syncthreads();

    for (int l=tid; l<L; l+=TPB){
        float4 pb = ((const float4*)pred_bboxes)[b*L + l];
        float st = stride_t[l];
        float p0 = pb.x*st, p1 = pb.y*st, p2 = pb.z*st, p3 = pb.w*st;
        float iw = fmaxf(fminf(gx2,p2)-fmaxf(gx1,p0), 0.f);
        float ih = fmaxf(fminf(gy2,p3)-fmaxf(gy1,p1), 0.f);
        float inter = iw*ih;
        float ap = (p2-p0)*(p3-p1);
        float iou = inter/(ag+ap-inter+EPS);
        ious[(size_t)bn*L + l] = iou;
        if (valid){
            float apx = anchor_points[2*l], apy = anchor_points[2*l+1];
            bool ing = (apx-gx1>EPS)&&(apy-gy1>EPS)&&(gx2-apx>EPS)&&(gy2-apy>EPS);
            if (ing){
                float v = sig[b*L+l]*pow6f(iou);
                int slot = atomicAdd(&scnt, 1);
                if (slot < CAP){ sval[slot]=v; sidx[slot]=l; }
            }
        }
    }
    __syncthreads();
    if (!valid) return;
    int cnt = scnt < CAP ? scnt : CAP;
    unsigned int nbit = 1u<<n;

    if (cnt <= TOPK){
        for (int i=tid; i<cnt; i+=TPB)
            atomicOr(&words[b*L + sidx[i]], nbit);
        return;
    }
    if (tid >= 64) return;
    float lv[LSLOT]; int li[LSLOT];
    #pragma unroll
    for (int k=0;k<LSLOT;k++){ lv[k]=-1.f; li[k]=0x7fffffff; }
    for (int i=tid; i<cnt; i+=64){
        float cv = sval[i]; int ci = sidx[i];
        #pragma unroll
        for (int k=0;k<LSLOT;k++){
            bool better = (cv>lv[k]) || (cv==lv[k] && ci<li[k]);
            if (better){
                float tv=lv[k]; lv[k]=cv; cv=tv;
                int   ti=li[k]; li[k]=ci; ci=ti;
            }
        }
    }
    for (int r=0;r<TOPK;r++){
        float bv=lv[0]; int bl=li[0];
        #pragma unroll
        for (int off=32; off>0; off>>=1){
            float ov = __shfl_xor(bv, off);
            int   oi = __shfl_xor(bl, off);
            if (ov>bv || (ov==bv && oi<bl)){ bv=ov; bl=oi; }
        }
        if (li[0]==bl){
            atomicOr(&words[b*L + bl], nbit);
            #pragma unroll
            for (int k=0;k<LSLOT-1;k++){ lv[k]=lv[k+1]; li[k]=li[k+1]; }
            lv[LSLOT-1]=-1.f; li[LSLOT-1]=0x7fffffff;
        }
    }
}

// K3: resolve multi-GT anchors (onehot argmax_n iou, incl. padded n — as the
// reference does), compact positive anchors, and feed per-GT rowmaxes via
// atomicMax on uint bit-patterns (valid: met,iou >= 0). Replaces k_rowmax.
__global__ void k_resolve(const float* __restrict__ ious,
                          const float* __restrict__ sig,
                          unsigned int* __restrict__ words,
                          unsigned int* __restrict__ rowmax_m,
                          unsigned int* __restrict__ rowmax_i,
                          int* __restrict__ poslist,
                          int* __restrict__ pcnt,
                          int B,int N,int L)
{
    int idx = blockIdx.x*blockDim.x + threadIdx.x;
    if (idx >= B*L) return;
    int b = idx / L, l = idx % L;
    unsigned int w = words[idx];
    if (!w) return;
    int n;
    if (__popc(w) > 1){
        float bv=-1e30f; int bbest=0;
        for (int nn=0;nn<N;nn++){
            float vv = ious[((size_t)(b*N+nn))*L + l];
            if (vv > bv){ bv=vv; bbest=nn; }
        }
        n = bbest;
        words[idx] = 1u<<n;
    } else {
        n = __ffs(w)-1;
    }
    float iou = ious[((size_t)(b*N+n))*L + l];
    float met = sig[idx]*pow6f(iou);
    atomicMax(&rowmax_m[b*N+n], __float_as_uint(met));
    atomicMax(&rowmax_i[b*N+n], __float_as_uint(iou));
    int slot = atomicAdd(pcnt, 1);
    poslist[slot] = idx;
}

// K5a: uniform per-anchor cls loss (all B*L anchors, coalesced, cheap).
__global__ void k_loss_all(const float* __restrict__ pred_scores,
                           const float* __restrict__ sig,
                           const float* __restrict__ ious,
                           const unsigned int* __restrict__ words,
                           const unsigned int* __restrict__ rowmax_m,
                           const unsigned int* __restrict__ rowmax_i,
                           const int* __restrict__ gt_class,
                           float* __restrict__ partials,
                           int B,int N,int L)
{
    int idx = blockIdx.x*blockDim.x + threadIdx.x;
    float a_score=0.f, a_cls=0.f;
    if (idx < B*L){
        int b=idx/L, l=idx%L;
        unsigned int w = words[idx];
        float assigned = 0.f;
        if (w){
            int n = __ffs(w)-1;
            float iou = ious[((size_t)(b*N+n))*L + l];
            float met = sig[idx]*pow6f(iou);
            float score = met/(__uint_as_float(rowmax_m[b*N+n])+EPS)
                          *__uint_as_float(rowmax_i[b*N+n]);
            if (gt_class[b*N+n]==0) assigned = score;
        }
        float logit = pred_scores[idx];
        float sg = sig[idx];
        float wg = sg - assigned; wg *= wg;
        a_cls = wg * bcef(logit, assigned);
        a_score = assigned;
    }
    #pragma unroll
    for (int off=32; off>0; off>>=1){
        a_score += __shfl_xor(a_score, off);
        a_cls   += __shfl_xor(a_cls,   off);
    }
    __shared__ float ws2[16][2];
    int wid = threadIdx.x>>6;
    if ((threadIdx.x&63)==0){ ws2[wid][0]=a_score; ws2[wid][1]=a_cls; }
    __syncthreads();
    if (threadIdx.x==0){
        float s0=0.f, s1=0.f;
        #pragma unroll
        for (int i=0;i<16;i++){ s0+=ws2[i][0]; s1+=ws2[i][1]; }
        float* row = partials + (size_t)blockIdx.x*8;
        row[0]=s0; row[1]=s1; row[2]=0.f; row[3]=0.f;
        row[4]=0.f; row[5]=0.f; row[6]=0.f; row[7]=0.f;
    }
}

// K5b: heavy giou/DFL/pose path over COMPACTED positives (dense waves,
// no load-imbalance tail). ~6.6k threads max.
__global__ void k_loss_pos(const float* __restrict__ pred_distri,
                           const float* __restrict__ pose_logits,
                           const float* __restrict__ anchor_points,
                           const float* __restrict__ stride_t,
                           const float* __restrict__ gt_bboxes,
                           const float* __restrict__ gt_poses,
                           const float* __restrict__ sigmas,
                           const int*   __restrict__ gt_class,
                           const float* __restrict__ pred_bboxes,
                           const float* __restrict__ sig,
                           const float* __restrict__ ious,
                           const unsigned int* __restrict__ words,
                           const unsigned int* __restrict__ rowmax_m,
                           const unsigned int* __restrict__ rowmax_i,
                           const int* __restrict__ poslist,
                           const int* __restrict__ pcnt,
                           float* __restrict__ partials, int rowbase,
                           int B,int N,int L,int J)
{
    int i = blockIdx.x*blockDim.x + threadIdx.x;
    int cnt = *pcnt;
    float a_giou=0,a_dfl=0,a_pos=0,a_kmf=0,a_preg=0,a_pcls=0;
    if (i < cnt){
        int idx = poslist[i];
        int b=idx/L, l=idx%L;
        int n = __ffs(words[idx])-1;
        float iou0 = ious[((size_t)(b*N+n))*L + l];
        float met = sig[idx]*pow6f(iou0);
        float score = met/(__uint_as_float(rowmax_m[b*N+n])+EPS)
                      *__uint_as_float(rowmax_i[b*N+n]);
        float assigned = (gt_class[b*N+n]==0) ? score : 0.f;
        a_pos = 1.f;
        float st = stride_t[l];
        const float4 gb4 = ((const float4*)gt_bboxes)[b*N+n];
        float ab0=gb4.x/st, ab1=gb4.y/st, ab2=gb4.z/st, ab3=gb4.w/st;
        float area = (ab2-ab0)*(ab3-ab1);
        float apx = anchor_points[2*l]/st, apy = anchor_points[2*l+1]/st;
        float bw = assigned;
        if (bw > 0.f){
            float4 pb = ((const float4*)pred_bboxes)[idx];
            float iw = fmaxf(fminf(pb.z,ab2)-fmaxf(pb.x,ab0),0.f);
            float ih = fmaxf(fminf(pb.w,ab3)-fmaxf(pb.y,ab1),0.f);
            float inter=iw*ih;
            float a1=(pb.z-pb.x)*(pb.w-pb.y);
            float a2=(ab2-ab0)*(ab3-ab1);
            float uni=a1+a2-inter+EPS;
            float iou=inter/uni;
            float cw=fmaxf(pb.z,ab2)-fminf(pb.x,ab0);
            float ch=fmaxf(pb.w,ab3)-fminf(pb.y,ab1);
            float ac=cw*ch+EPS;
            float g = 1.f-(iou-(ac-uni)/ac);
            a_giou = g*bw;
            // DFL: vectorized load, statically-indexed max/sumexp; the two
            // tl-gathers hit hot cache lines.
            float t4[4] = { apx-ab0, apy-ab1, ab2-apx, ab3-apy };
            const float* pdist = pred_distri + (size_t)idx*68;
            const float4* pd4 = (const float4*)pdist;
            float v[68];
            #pragma unroll
            for (int q=0;q<17;q++){ float4 qq=pd4[q]; v[4*q]=qq.x; v[4*q+1]=qq.y; v[4*q+2]=qq.z; v[4*q+3]=qq.w; }
            float dfl=0.f;
            #pragma unroll
            for (int s2=0;s2<4;s2++){
                float tt = fminf(fmaxf(t4[s2],0.f),(float)REG_MAX-0.01f);
                int tl = (int)floorf(tt);
                float wl = (float)tl + 1.f - tt;
                float m=-1e30f;
                #pragma unroll
                for (int q=0;q<=REG_MAX;q++) m=fmaxf(m,v[s2*17+q]);
                float se=0.f;
                #pragma unroll
                for (int q=0;q<=REG_MAX;q++) se+=expf(v[s2*17+q]-m);
                float lse = m + logf(se);
                float ll = -(pdist[s2*17+tl]-lse);
                float lr = -(pdist[s2*17+tl+1]-lse);
                dfl += ll*wl + lr*(1.f-wl);
            }
            a_dfl = dfl*0.25f*bw;
        }
        const float* gp = gt_poses + ((size_t)(b*N+n))*J*3;
        const float* pl = pose_logits + (size_t)idx*J*3;
        for (int j=0;j<J;j++){
            float gx=gp[3*j]/st, gy=gp[3*j+1]/st, vis=gp[3*j+2];
            float px=pl[3*j]+apx, py=pl[3*j+1]+apy, pz=pl[3*j+2];
            float kmf = (vis!=0.f)?1.f:0.f;
            float dx=px-gx, dy=py-gy;
            float d = dx*dx+dy*dy;
            float s2g = 2.f*sigmas[j]; s2g*=s2g;
            float e = d/s2g/(area+EPS)/2.f;
            a_preg += (1.f-expf(-e))*kmf;
            a_kmf  += kmf;
            a_pcls += bcef(pz, kmf);
        }
    }
    float acc[6] = {a_giou,a_dfl,a_pos,a_kmf,a_preg,a_pcls};
    #pragma unroll
    for (int k=0;k<6;k++){
        #pragma unroll
        for (int off=32; off>0; off>>=1) acc[k] += __shfl_xor(acc[k], off);
    }
    __shared__ float wsum[4][6];
    int wid = threadIdx.x>>6;
    if ((threadIdx.x&63)==0){
        #pragma unroll
        for (int k=0;k<6;k++) wsum[wid][k]=acc[k];
    }
    __syncthreads();
    if (threadIdx.x==0){
        float* row = partials + (size_t)(rowbase+blockIdx.x)*8;
        row[0]=0.f; row[1]=0.f;
        #pragma unroll
        for (int k=0;k<6;k++)
            row[2+k]=wsum[0][k]+wsum[1][k]+wsum[2][k]+wsum[3][k];
    }
}

// K6: deterministic parallel final reduction + loss assembly -> 7 floats
__global__ void k_final(const float* __restrict__ partials, int nblk, int J,
                        float* __restrict__ out)
{
    __shared__ float red[256][9];
    int tid = threadIdx.x;
    float acc[8] = {0,0,0,0,0,0,0,0};
    for (int i=tid; i<nblk; i+=256){
        const float4* p = (const float4*)(partials + (size_t)i*8);
        float4 a = p[0], b = p[1];
        acc[0]+=a.x; acc[1]+=a.y; acc[2]+=a.z; acc[3]+=a.w;
        acc[4]+=b.x; acc[5]+=b.y; acc[6]+=b.z; acc[7]+=b.w;
    }
    #pragma unroll
    for (int k=0;k<8;k++) red[tid][k]=acc[k];
    __syncthreads();
    for (int s=128;s>0;s>>=1){
        if (tid<s){
            #pragma unroll
            for (int k=0;k<8;k++) red[tid][k]+=red[tid+s][k];
        }
        __syncthreads();
    }
    if (tid==0){
        float ass  = fmaxf(red[0][0],1.f);
        float lcls = red[0][1]/ass;
        float liou = red[0][2]/ass;
        float ldfl = red[0][3]/ass;
        float npk  = fmaxf(red[0][4]*(float)J,1.f);
        float factor = npk/(red[0][5]+EPS);
        float preg = factor*red[0][6]/npk;
        float pcls = red[0][7]/npk;
        float loss = lcls + 2.5f*liou + 0.5f*ldfl + pcls + preg;
        out[0]=loss; out[1]=lcls; out[2]=liou; out[3]=ldfl;
        out[4]=pcls; out[5]=preg; out[6]=loss;
    }
}

extern "C" void kernel_launch(void* const* d_in, const int* in_sizes, int n_in,
                              void* d_out, int out_size, void* d_ws, size_t ws_size,
                              hipStream_t stream)
{
    const float* pred_scores   = (const float*)d_in[0];
    const float* pred_distri   = (const float*)d_in[1];
    const float* pose_logits   = (const float*)d_in[2];
    const float* anchor_points = (const float*)d_in[3];
    const float* stride_t      = (const float*)d_in[4];
    const float* gt_bboxes     = (const float*)d_in[5];
    const float* pad_mask      = (const float*)d_in[6];
    const float* gt_poses      = (const float*)d_in[7];
    const float* sigmas        = (const float*)d_in[8];
    const int*   gt_class      = (const int*)d_in[9];

    int L = in_sizes[3]/2;
    int B = in_sizes[0]/L;
    int N = in_sizes[5]/(B*4);
    int J = in_sizes[8];

    char* ws = (char*)d_ws;
    size_t off=0;
    auto alloc=[&](size_t bytes)->void*{
        size_t cur=off; off += (bytes+255)/256*256; return (void*)(ws+cur);
    };
    float* ious           = (float*)alloc((size_t)B*N*L*4);
    float* pred_bboxes    = (float*)alloc((size_t)B*L*4*4);
    float* sig            = (float*)alloc((size_t)B*L*4);
    unsigned int* words   = (unsigned int*)alloc((size_t)B*L*4);
    unsigned int* rowmax_m= (unsigned int*)alloc((size_t)B*N*4);
    unsigned int* rowmax_i= (unsigned int*)alloc((size_t)B*N*4);
    int maxpos = B*N*TOPK;
    int* poslist          = (int*)alloc((size_t)maxpos*4);
    int* pcnt             = (int*)alloc(256);
    int nblk256  = (B*L+255)/256;
    int nblkA    = (B*L+1023)/1024;
    int nblkP    = (maxpos+255)/256;
    float* partials       = (float*)alloc((size_t)(nblkA+nblkP)*8*4);
    (void)ws_size; (void)n_in; (void)out_size;

    k_decode<<<nblk256,256,0,stream>>>(pred_scores,pred_distri,anchor_points,
                                       stride_t,pred_bboxes,sig,
                                       words,rowmax_m,rowmax_i,pcnt,B,N,L);
    k_assign_topk<<<B*N,TPB,0,stream>>>(pred_bboxes,sig,anchor_points,stride_t,
                                        gt_bboxes,pad_mask,ious,words,B,N,L);
    k_resolve<<<nblk256,256,0,stream>>>(ious,sig,words,rowmax_m,rowmax_i,
                                        poslist,pcnt,B,N,L);
    k_loss_all<<<nblkA,1024,0,stream>>>(pred_scores,sig,ious,words,
                                        rowmax_m,rowmax_i,gt_class,
                                        partials,B,N,L);
    k_loss_pos<<<nblkP,256,0,stream>>>(pred_distri,pose_logits,anchor_points,
                                       stride_t,gt_bboxes,gt_poses,sigmas,
                                       gt_class,pred_bboxes,sig,ious,words,
                                       rowmax_m,rowmax_i,poslist,pcnt,
                                       partials,nblkA,B,N,L,J);
    k_final<<<1,256,0,stream>>>(partials,nblkA+nblkP,J,(float*)d_out);
}